// Round 14
// baseline (106.340 us; speedup 1.0000x reference)
//
#include <hip/hip_runtime.h>
#include <hip/hip_bf16.h>

#define E_ 8
#define B_ 8
#define S_ 2048
#define D_ 512
#define R_ 128
#define M_TOT (B_ * S_)   // 16384

typedef __attribute__((ext_vector_type(8))) short bf16x8;
typedef __attribute__((ext_vector_type(4))) float f32x4;
typedef __attribute__((ext_vector_type(4))) short s16x4;

__device__ __forceinline__ void gload_lds16(void* lds, const void* g) {
  __builtin_amdgcn_global_load_lds(
      (const __attribute__((address_space(1))) void*)g,
      (__attribute__((address_space(3))) void*)lds, 16, 0, 0);
}

// ---------------------------------------------------------------------------
// Fused prep kernel (R13): rot one-shot slab | W tail | x -> bf16 (nt loads)
// ---------------------------------------------------------------------------
#define ROT_B 32
#define WT_B 2048
#define CX_B 4096
__global__ __launch_bounds__(256) void prep_fused(
    const float* __restrict__ x, const float* __restrict__ theta,
    const float* __restrict__ pw, __hip_bfloat16* __restrict__ xb,
    __hip_bfloat16* __restrict__ Wb) {
  int blk = blockIdx.x;
  int t = threadIdx.x;
  if (blk < ROT_B) {
    __shared__ float cs[R_], ss[R_];
    __shared__ float Pch[128][130];
    __shared__ __hip_bfloat16 Wch[128][130];
    int e = blk >> 2;
    int r0 = (blk & 3) * 128;
    if (t < R_) {
      float a = tanhf(theta[e * R_ + t]) * 0.1f;
      cs[t] = cosf(a);
      ss[t] = sinf(a);
    }
    const float* Pe = pw + (size_t)e * D_ * D_;
    __hip_bfloat16* We = Wb + (size_t)e * D_ * D_;
#pragma unroll 8
    for (int it = 0; it < 64; ++it) {
      int row = it * 2 + (t >> 7);
      int col = t & 127;
      Pch[row][col] = Pe[(size_t)(r0 + row) * D_ + col];
    }
    if (t < 128) Pch[t][128] = Pe[(size_t)(r0 + t) * D_ + 128];
    __syncthreads();
    if (t < 128) {
      float u = Pch[t][0];
#pragma unroll 16
      for (int k = 0; k < R_; ++k) {
        float pj = Pch[t][k + 1];
        Wch[t][k + 1] = __float2bfloat16(cs[k] * pj - ss[k] * u);
        u = cs[k] * u + ss[k] * pj;
      }
      Wch[t][0] = __float2bfloat16(u);
    }
    __syncthreads();
#pragma unroll 8
    for (int it = 0; it < 64; ++it) {
      int row = it * 2 + (t >> 7);
      int col = t & 127;
      We[(size_t)(r0 + row) * D_ + col] = Wch[row][col];
    }
    if (t < 128) We[(size_t)(r0 + t) * D_ + 128] = Wch[t][128];
  } else if (blk < ROT_B + WT_B) {
    int g = (blk - ROT_B) * 256 + t;
    int gidx = g & 127;
    if (gidx < 32) return;
    float4 v = ((const float4*)pw)[g];
    union { short4 s; __hip_bfloat16 h[4]; } u;
    u.h[0] = __float2bfloat16(v.x);
    u.h[1] = __float2bfloat16(v.y);
    u.h[2] = __float2bfloat16(v.z);
    u.h[3] = __float2bfloat16(v.w);
    if (gidx > 32) {
      ((short4*)Wb)[g] = u.s;
    } else {
      Wb[(size_t)g * 4 + 1] = u.h[1];
      Wb[(size_t)g * 4 + 2] = u.h[2];
      Wb[(size_t)g * 4 + 3] = u.h[3];
    }
  } else {
    int i = (blk - ROT_B - WT_B) * 256 + t;
#pragma unroll
    for (int rep = 0; rep < 2; ++rep) {
      int idx = i + rep * (CX_B * 256);
      f32x4 v = __builtin_nontemporal_load(&((const f32x4*)x)[idx]);
      union { s16x4 s; __hip_bfloat16 h[4]; } u;
      u.h[0] = __float2bfloat16(v.x);
      u.h[1] = __float2bfloat16(v.y);
      u.h[2] = __float2bfloat16(v.z);
      u.h[3] = __float2bfloat16(v.w);
      ((s16x4*)xb)[idx] = u.s;
    }
  }
}

// ---------------------------------------------------------------------------
// GEMM: out[e] = Xb @ Wb[e]^T (NT). Same 256x128 tile / BK=32 dbuf /
// counted-vmcnt ring / XCD swizzle / nt-store epilogue as R12 — but
// 8 WAVES of 64x64 (acc=64 VGPR, __launch_bounds__(512,4) caps VGPR at 128)
// -> 16 waves/CU (50% occupancy, was 25%): doubles latency hiding.
// vmcnt: 3 loads/wave/tile -> steady-state vmcnt(3), tail vmcnt(0).
// Epilogue: per-wave private LDS strip (no cross-wave barriers), 256B
// contiguous nontemporal f32x4 stores.
// ---------------------------------------------------------------------------
__global__ __launch_bounds__(512, 4) void gemm_xw(
    const __hip_bfloat16* __restrict__ Xb,   // [M_TOT][512]
    const __hip_bfloat16* __restrict__ Wb,   // [E][512][512] rows=o, cols=d
    float* __restrict__ out)                 // [E][M_TOT][512]
{
  constexpr int BM = 256, BN = 128, BK = 32;
  constexpr int KD = D_, ND = D_;
  constexpr int NT = KD / BK;  // 16
  // 48 KB pool: K-loop As 2x16K + Bs 2x8K; epilogue reuses 34.8 KB.
  __shared__ __align__(16) char smem[49152];
  __hip_bfloat16 (*As)[BM * BK] =
      (__hip_bfloat16 (*)[BM * BK]) & smem[0];         // 2 x 16 KB
  __hip_bfloat16 (*Bs)[BN * BK] =
      (__hip_bfloat16 (*)[BN * BK]) & smem[32768];     // 2 x 8 KB
  float* Lep = (float*)&smem[0];                       // 8 x 16 x 68 f32

  int bx = blockIdx.x;            // 2048 blocks
  int xcd = bx & 7, c = bx >> 3;  // chunk c in [0,256) per XCD
  int e = c >> 5;                 // 0..7  (e-major within XCD)
  int msub = (c >> 2) & 7;        // 0..7
  int nt = c & 3;                 // 0..3
  int mt = xcd * 8 + msub;        // 0..63

  int tid = threadIdx.x;
  int wave = tid >> 6, lane = tid & 63;
  int lr = lane & 15, lk = lane >> 4;
  int wm = wave >> 1, wn = wave & 1;   // 4x2 waves; wave-tile 64x64

  const __hip_bfloat16* Ag = Xb + (size_t)(mt * BM) * KD;
  const __hip_bfloat16* Bg = Wb + ((size_t)e * ND + (size_t)nt * BN) * KD;

  // staging: lane -> (row = lane>>2 of 16, chunk = lane&3); linear LDS dest.
  int srow = lane >> 2;
  int scol = (lane & 3) * 8;

  // fragment reads: addr = row*64B + lk*16B (bank-uniform at 64B stride)
  int aoff = (wm * 64 + lr) * BK + lk * 8;
  int boff = (wn * 64 + lr) * BK + lk * 8;

  f32x4 acc[4][4];
#pragma unroll
  for (int i = 0; i < 4; ++i)
#pragma unroll
    for (int j = 0; j < 4; ++j) acc[i][j] = (f32x4){0.f, 0.f, 0.f, 0.f};

  // per wave per tile: A 2 gloads (32 rows), B 1 gload (16 rows) = 3 loads
#define STAGE(buf, t)                                                        \
  {                                                                          \
    _Pragma("unroll") for (int g = 0; g < 2; ++g) {                          \
      int rb = wave * 32 + g * 16;                                           \
      gload_lds16(&As[buf][rb * BK],                                         \
                  Ag + (size_t)(rb + srow) * KD + (t) * BK + scol);          \
    }                                                                        \
    {                                                                        \
      int rb = wave * 16;                                                    \
      gload_lds16(&Bs[buf][rb * BK],                                         \
                  Bg + (size_t)(rb + srow) * KD + (t) * BK + scol);          \
    }                                                                        \
  }

  STAGE(0, 0);
  STAGE(1, 1);

#pragma unroll
  for (int t = 0; t < NT; ++t) {
    int buf = t & 1;
    // tile t resident once <=3 newer loads (tile t+1) remain in flight
    if (t < NT - 1) {
      asm volatile("s_waitcnt vmcnt(3)" ::: "memory");
    } else {
      asm volatile("s_waitcnt vmcnt(0)" ::: "memory");
    }
    __builtin_amdgcn_s_barrier();   // tile t visible to all 8 waves

    bf16x8 af[4], bfr[4];
#pragma unroll
    for (int ni = 0; ni < 4; ++ni)
      bfr[ni] = *(const bf16x8*)&Bs[buf][boff + ni * 16 * BK];
#pragma unroll
    for (int mi = 0; mi < 4; ++mi)
      af[mi] = *(const bf16x8*)&As[buf][aoff + mi * 16 * BK];
    __builtin_amdgcn_s_setprio(1);
#pragma unroll
    for (int mi = 0; mi < 4; ++mi)
#pragma unroll
      for (int ni = 0; ni < 4; ++ni)
        acc[mi][ni] = __builtin_amdgcn_mfma_f32_16x16x32_bf16(
            af[mi], bfr[ni], acc[mi][ni], 0, 0, 0);
    __builtin_amdgcn_s_setprio(0);

    // all ds_reads of this tile drained before DMA may overwrite the slot
    asm volatile("s_waitcnt lgkmcnt(0)" ::: "memory");
    __builtin_amdgcn_sched_barrier(0);
    __builtin_amdgcn_s_barrier();
    if (t + 2 < NT) STAGE(buf, t + 2);
  }
#undef STAGE

  // ---- write-coalesced epilogue (per-wave private strip, nt stores) ----
  // C/D frag layout: col = lane&15 (lr), row = lk*4 + q   [m89]
  // Wave owns 64x64 at (wm*64, wn*64). Round r: rows [r*16, +16) of the
  // wave-tile staged in Lh[wave][16][68], then read back as f32x4 rows
  // (16 lanes x 16B = 256B contiguous per row, 4 rows per instruction).
  size_t obase = (size_t)e * M_TOT * ND;
  int row0 = mt * BM + wm * 64;
  int col0 = nt * BN + wn * 64;
  float* Lh = Lep + (size_t)wave * (16 * 68);
#pragma unroll
  for (int r = 0; r < 4; ++r) {
#pragma unroll
    for (int ni = 0; ni < 4; ++ni)
#pragma unroll
      for (int q = 0; q < 4; ++q)
        Lh[(lk * 4 + q) * 68 + ni * 16 + lr] = acc[r][ni][q];
    asm volatile("s_waitcnt lgkmcnt(0)" ::: "memory");  // own-region, no bar
    __builtin_amdgcn_sched_barrier(0);
#pragma unroll
    for (int j = 0; j < 4; ++j) {
      int el = j * 64 + lane;        // 256 f32x4 in 16x16 grid
      int lrow = el >> 4, lc4 = el & 15;
      f32x4 v = *(const f32x4*)&Lh[lrow * 68 + lc4 * 4];
      int grow = row0 + r * 16 + lrow;
      __builtin_nontemporal_store(
          v, (f32x4*)&out[obase + (size_t)grow * ND + col0 + lc4 * 4]);
    }
    asm volatile("s_waitcnt lgkmcnt(0)" ::: "memory");
    __builtin_amdgcn_sched_barrier(0);
  }
}

extern "C" void kernel_launch(void* const* d_in, const int* in_sizes, int n_in,
                              void* d_out, int out_size, void* d_ws, size_t ws_size,
                              hipStream_t stream) {
  const float* x = (const float*)d_in[0];        // [B][S][D] f32
  const float* theta = (const float*)d_in[1];    // [E][R] f32
  const float* proj_w = (const float*)d_in[2];   // [E][D][D] f32
  float* out = (float*)d_out;                    // [E][B][S][D] f32

  __hip_bfloat16* xb = (__hip_bfloat16*)d_ws;                          // 16 MB
  __hip_bfloat16* Wb = (__hip_bfloat16*)((char*)d_ws +
                        (size_t)M_TOT * D_ * sizeof(__hip_bfloat16));  // 4 MB

  hipLaunchKernelGGL(prep_fused, dim3(ROT_B + WT_B + CX_B), dim3(256), 0,
                     stream, x, theta, proj_w, xb, Wb);
  // grid: (M_TOT/256)=64 mt  x  8 e  x  (512/128)=4 nt  = 2048 blocks
  hipLaunchKernelGGL(gemm_xw, dim3(2048), dim3(512), 0, stream, xb, Wb, out);
}